// Round 2
// baseline (238.386 us; speedup 1.0000x reference)
//
#include <hip/hip_runtime.h>

#define DIM    2048
#define SEQ    4096
#define BATCH  4
#define KW     4
#define TCHUNK 8

typedef float fvec4 __attribute__((ext_vector_type(4)));  // native vector for builtins

constexpr int D4       = DIM / 4;              // 512 float4 columns
constexpr int NT       = SEQ / TCHUNK;         // 512 time chunks
constexpr int NCHUNK   = BATCH * NT * D4;      // 1048576 total chunks
constexpr int NBLOCK   = 1024;                 // 4 blocks/CU -> 16 waves/CU resident
constexpr int BLOCKSZ  = 256;
constexpr int NTHREADS = NBLOCK * BLOCKSZ;     // 262144
constexpr int ITERS    = NCHUNK / NTHREADS;    // 4 chunks per thread

// Persistent-wave, 2-deep software-pipelined streaming stencil.
// Previous build (one chunk per thread, grid fully resident once) ran as
// disjoint machine-wide read phase -> compute -> store phase: 2.5 TB/s.
// Here each thread iterates 4 chunks double-buffered: chunk i+1's 11 loads
// are in flight while chunk i computes + stores -> reads and writes overlap
// continuously (copy-benchmark structure, which reaches 6.3 TB/s).
// Thread->chunk map: d4 (channel quad) and tc (time chunk) are loop-invariant;
// iterations step the batch index. Weights load once; halo branch uniform.
__global__ __launch_bounds__(BLOCKSZ, 4) void ShortConv1D_78855599554935_kernel(
    const float* __restrict__ x, const float* __restrict__ w,
    const float* __restrict__ bias, float* __restrict__ out)
{
    int idx = blockIdx.x * BLOCKSZ + threadIdx.x;
    int d4  = idx & (D4 - 1);                  // constant across iterations
    int tc  = (idx >> 9) & (NT - 1);           // constant across iterations

    const fvec4* __restrict__ x4 = (const fvec4*)x;
    const fvec4* __restrict__ w4 = (const fvec4*)w;
    const fvec4* __restrict__ b4 = (const fvec4*)bias;
    fvec4* __restrict__ o4 = (fvec4*)out;

    // weight rows for channels d = 4*d4 + j  (w is [D,K] row-major, K=4)
    fvec4 w0 = w4[d4 * 4 + 0];
    fvec4 w1 = w4[d4 * 4 + 1];
    fvec4 w2 = w4[d4 * 4 + 2];
    fvec4 w3 = w4[d4 * 4 + 3];
    fvec4 bv = b4[d4];

    // base (in fvec4 units) for iteration k: batch bb = k
    long base0 = (long)tc * TCHUNK * D4 + (long)d4;
    constexpr long BSTRIDE = (long)SEQ * D4;   // one batch

    fvec4 xa[TCHUNK + 3], xb[TCHUNK + 3];

#define LOADCH(xv, base)                                                    \
    do {                                                                    \
        if (tc > 0) {                    /* wave-uniform, loop-invariant */ \
            xv[0] = x4[(base) - 3 * D4];                                    \
            xv[1] = x4[(base) - 2 * D4];                                    \
            xv[2] = x4[(base) - 1 * D4];                                    \
        } else {                                                            \
            xv[0] = (fvec4)(0.f);                                           \
            xv[1] = (fvec4)(0.f);                                           \
            xv[2] = (fvec4)(0.f);                                           \
        }                                                                   \
        _Pragma("unroll")                                                   \
        for (int t = 0; t < TCHUNK; ++t) xv[3 + t] = x4[(base) + t * D4];   \
    } while (0)

#define STORECH(xv, base)                                                   \
    do {                                                                    \
        _Pragma("unroll")                                                   \
        for (int t = 0; t < TCHUNK; ++t) {                                  \
            fvec4 a  = xv[t];                                               \
            fvec4 bq = xv[t + 1];                                           \
            fvec4 cc = xv[t + 2];                                           \
            fvec4 dd = xv[t + 3];                                           \
            fvec4 r;                                                        \
            r.x = bv.x + w0.x * a.x + w0.y * bq.x + w0.z * cc.x + w0.w * dd.x; \
            r.y = bv.y + w1.x * a.y + w1.y * bq.y + w1.z * cc.y + w1.w * dd.y; \
            r.z = bv.z + w2.x * a.z + w2.y * bq.z + w2.z * cc.z + w2.w * dd.z; \
            r.w = bv.w + w3.x * a.w + w3.y * bq.w + w3.z * cc.w + w3.w * dd.w; \
            __builtin_nontemporal_store(r, &o4[(base) + t * D4]);           \
        }                                                                   \
    } while (0)

    // ---- prologue: fill pipe with chunk 0 ----
    LOADCH(xa, base0);
    __builtin_amdgcn_sched_barrier(0);   // loads issue before anything below

    // ---- steady state: 2-deep double-buffer, statically unrolled ----
#pragma unroll
    for (int it = 0; it < ITERS; it += 2) {
        long baseB = base0 + (long)(it + 1) * BSTRIDE;
        LOADCH(xb, baseB);                       // prefetch next chunk
        __builtin_amdgcn_sched_barrier(0);       // pin: issue before compute
        STORECH(xa, base0 + (long)it * BSTRIDE); // drain + store current

        if (it + 2 < ITERS) {                    // static after unroll
            LOADCH(xa, base0 + (long)(it + 2) * BSTRIDE);
            __builtin_amdgcn_sched_barrier(0);
        }
        STORECH(xb, baseB);
    }

#undef LOADCH
#undef STORECH
}

extern "C" void kernel_launch(void* const* d_in, const int* in_sizes, int n_in,
                              void* d_out, int out_size, void* d_ws, size_t ws_size,
                              hipStream_t stream) {
    const float* x = (const float*)d_in[0];
    const float* w = (const float*)d_in[1];
    const float* b = (const float*)d_in[2];
    float* out = (float*)d_out;

    ShortConv1D_78855599554935_kernel<<<NBLOCK, BLOCKSZ, 0, stream>>>(x, w, b, out);
}